// Round 1
// baseline (19.636 us; speedup 1.0000x reference)
//
#include <hip/hip_runtime.h>
#include <math.h>

#define N_PTS 131072
#define UNITS 256
#define BLOCK 256
#define GRID  (N_PTS / BLOCK)   // 512 blocks, one thread per point

// Main kernel: per-point RBF sums + squared-error partials per block.
__global__ __launch_bounds__(BLOCK) void rbf_pinn_main(
    const float* __restrict__ x, const float* __restrict__ y,
    const float* __restrict__ u, const float* __restrict__ centers,
    const float* __restrict__ W, const float* __restrict__ eps,
    const float* __restrict__ delta, const float* __restrict__ gam,
    const int* __restrict__ iters, float* __restrict__ partial)
{
    __shared__ float s_cx[UNITS], s_cy[UNITS], s_w[UNITS];
    const int t = threadIdx.x;
    // Stage centers/weights once per block (UNITS == BLOCK == 256).
    s_cx[t] = centers[2 * t + 0];
    s_cy[t] = centers[2 * t + 1];
    s_w[t]  = W[t];
    __syncthreads();

    const int i = blockIdx.x * BLOCK + t;
    const float xi = x[i];
    const float yi = y[i];
    const float ui = u[i];

    float up = 0.f;   // u_pred
    float sh = 0.f;   // u + 2*laplace(u) + biharmonic(u)
    const float c = -0.72134752044448170368f;  // -0.5 * log2(e)

    #pragma unroll 8
    for (int j = 0; j < UNITS; ++j) {
        float dx = xi - s_cx[j];
        float dy = yi - s_cy[j];
        float s  = fmaf(dy, dy, dx * dx);
        float e  = __builtin_amdgcn_exp2f(c * s);     // exp(-0.5*s), s in [0,2]
        float ew = e * s_w[j];
        up += ew;
        float poly = fmaf(s, s - 6.f, 5.f);           // s^2 - 6s + 5
        sh = fmaf(ew, poly, sh);
    }

    // Residual stage selection (iterations is a device input; 40000 -> else).
    const int   it   = iters[0];
    const float epsv = eps[0];
    const float dl   = delta[0];
    const float gm   = gam[0];
    float c2, c3;
    if (it < 10000)      { c2 = 0.0f; c3 = 0.0f; }
    else if (it < 20000) { c2 = 0.3f; c3 = 0.0f; }
    else if (it < 30000) { c2 = 0.7f; c3 = 0.3f; }
    else                 { c2 = 1.0f; c3 = 1.0f; }

    const float up2 = up * up;
    const float res = epsv * up - c2 * dl * up2 - c3 * gm * up2 * up - sh;
    const float d   = up - ui;

    float a0 = d * d;     // (u_pred - u)^2
    float a1 = ui * ui;   // u^2
    float a2 = res * res; // pde_residual^2

    // Wave (64-lane) shuffle reduction, then cross-wave via LDS.
    #pragma unroll
    for (int o = 32; o > 0; o >>= 1) {
        a0 += __shfl_down(a0, o);
        a1 += __shfl_down(a1, o);
        a2 += __shfl_down(a2, o);
    }
    __shared__ float s_r[3][BLOCK / 64];
    const int lane = t & 63;
    const int wv   = t >> 6;
    if (lane == 0) { s_r[0][wv] = a0; s_r[1][wv] = a1; s_r[2][wv] = a2; }
    __syncthreads();
    if (t == 0) {
        float r0 = 0.f, r1 = 0.f, r2 = 0.f;
        #pragma unroll
        for (int w2 = 0; w2 < BLOCK / 64; ++w2) {
            r0 += s_r[0][w2]; r1 += s_r[1][w2]; r2 += s_r[2][w2];
        }
        partial[0 * GRID + blockIdx.x] = r0;
        partial[1 * GRID + blockIdx.x] = r1;
        partial[2 * GRID + blockIdx.x] = r2;
    }
}

// Final reduction over 512 per-block partials + loss assembly.
__global__ __launch_bounds__(256) void rbf_pinn_final(
    const float* __restrict__ partial, const float* __restrict__ eps,
    const int* __restrict__ iters, float* __restrict__ out)
{
    const int t = threadIdx.x;
    float a0 = 0.f, a1 = 0.f, a2 = 0.f;
    for (int k = t; k < GRID; k += 256) {
        a0 += partial[0 * GRID + k];
        a1 += partial[1 * GRID + k];
        a2 += partial[2 * GRID + k];
    }
    #pragma unroll
    for (int o = 32; o > 0; o >>= 1) {
        a0 += __shfl_down(a0, o);
        a1 += __shfl_down(a1, o);
        a2 += __shfl_down(a2, o);
    }
    __shared__ float s_r[3][4];
    const int lane = t & 63;
    const int wv   = t >> 6;
    if (lane == 0) { s_r[0][wv] = a0; s_r[1][wv] = a1; s_r[2][wv] = a2; }
    __syncthreads();
    if (t == 0) {
        float S0 = 0.f, S1 = 0.f, S2 = 0.f;
        #pragma unroll
        for (int w2 = 0; w2 < 4; ++w2) { S0 += s_r[0][w2]; S1 += s_r[1][w2]; S2 += s_r[2][w2]; }
        const float loss_u   = S0 / S1;                 // mean ratios: N cancels
        const float loss_pde = S2 / (float)N_PTS;
        const int it = iters[0];
        float cw;
        if (it < 10000)      cw = 0.1f;
        else if (it < 20000) cw = 0.3f;
        else if (it < 30000) cw = 0.6f;
        else                 cw = 1.0f;
        const float e = eps[0];
        const float b0 = fmaxf(0.f, e - 0.8f);
        const float b1 = fmaxf(0.f, 0.2f - e);
        const float eps_bp = b0 * b0 + b1 * b1;
        const float loss1 = 0.1f * loss_u + cw * loss_pde + 0.01f * eps_bp;
        out[0] = loss1;
        out[1] = loss_u;
        out[2] = loss_pde;
    }
}

extern "C" void kernel_launch(void* const* d_in, const int* in_sizes, int n_in,
                              void* d_out, int out_size, void* d_ws, size_t ws_size,
                              hipStream_t stream) {
    const float* x       = (const float*)d_in[0];
    const float* y       = (const float*)d_in[1];
    const float* u       = (const float*)d_in[2];
    const float* centers = (const float*)d_in[3];
    const float* W       = (const float*)d_in[4];
    const float* eps     = (const float*)d_in[5];
    const float* delta   = (const float*)d_in[6];
    const float* gam     = (const float*)d_in[7];
    const int*   iters   = (const int*)d_in[8];
    float* out = (float*)d_out;
    float* partial = (float*)d_ws;  // 3 * GRID floats = 6 KB

    rbf_pinn_main<<<GRID, BLOCK, 0, stream>>>(x, y, u, centers, W, eps, delta,
                                              gam, iters, partial);
    rbf_pinn_final<<<1, 256, 0, stream>>>(partial, eps, iters, out);
}